// Round 9
// baseline (424.005 us; speedup 1.0000x reference)
//
#include <hip/hip_runtime.h>
#include <hip/hip_bf16.h>

// ArcFace fused — ROUND 9: ablation round.
//   prep_afrag : emb f32 -> bf16 A-fragments (512 KB, L2-resident)
//   wt_kernel  : w f32 -> bf16 B-fragments + rsqrt col norms (near BW ceiling, ~55us)
//   abl_kloop  : DIAGNOSTIC. r8 main's K-loop verbatim (6 dwordx4 + 8 MFMA + tgt scan
//                per step), epilogue replaced by checksum->ws. Same grid. Separates
//                K-loop cost from epilogue cost via (total, top-5) arithmetic.
//   arcface_main: r8 K-loop + FIXED-SHIFT softmax epilogue: logits in [-64,64] =>
//                exp(l-20) in [e^-84, e^44], all normal f32 -> per-column max pass
//                deleted (saves 2 barriers + reduction).

static constexpr int DIM    = 512;
static constexpr int NROWS  = 512;
static constexpr int NCLS   = 100000;
static constexpr int BC     = 32;              // columns per block
static constexpr int BK     = 32;              // K per step
static constexpr int NSTEP  = DIM / BK;        // 16
static constexpr int MT     = NROWS / 16;      // 32
static constexpr int NBLK   = NCLS / BC;       // 3125 exact

static constexpr float COS_M = 0.87758256189037271611f;  // cos(0.5)
static constexpr float SIN_M = 0.47942553860420300027f;  // sin(0.5)
static constexpr float SCALE = 64.0f;
static constexpr float SHIFT = 20.0f;          // fixed softmax shift (see header)

typedef __attribute__((ext_vector_type(8))) short bf16x8;
typedef __attribute__((ext_vector_type(4))) float f32x4;

#define MFMA16(A, B, C) __builtin_amdgcn_mfma_f32_16x16x32_bf16((A), (B), (C), 0, 0, 0)

__device__ __forceinline__ unsigned short f2bf(float f) {
  union { float f; unsigned u; } v; v.f = f;
  unsigned u = v.u;
  return (unsigned short)((u + 0x7FFFu + ((u >> 16) & 1u)) >> 16);
}

// ---------------------------------------------------------------------------
__global__ void prep_afrag(const float* __restrict__ emb,
                           unsigned short* __restrict__ afrag) {
  const int idx = blockIdx.x * blockDim.x + threadIdx.x;  // 0..32767
  const int l  = idx & 63;
  const int mt = (idx >> 6) & 31;
  const int ks = idx >> 11;
  const int row = mt * 16 + (l & 15);
  const int k0  = ks * 32 + (l >> 4) * 8;

  unsigned short t[8];
#pragma unroll
  for (int j = 0; j < 8; ++j) t[j] = f2bf(emb[row * DIM + k0 + j]);

  uint4 v;
  v.x = (unsigned)t[0] | ((unsigned)t[1] << 16);
  v.y = (unsigned)t[2] | ((unsigned)t[3] << 16);
  v.z = (unsigned)t[4] | ((unsigned)t[5] << 16);
  v.w = (unsigned)t[6] | ((unsigned)t[7] << 16);
  *reinterpret_cast<uint4*>(&afrag[(size_t)idx * 8]) = v;
}

// ---------------------------------------------------------------------------
__global__ __launch_bounds__(256)
void wt_kernel(const float* __restrict__ w,
               unsigned short* __restrict__ bfrag,
               float* __restrict__ rnorm) {
  __shared__ float S[32][33];
  __shared__ float NRM[32][32];

  const int t  = threadIdx.x;
  const int cb = blockIdx.x;
  const int c0 = cb * 32;

  const int rk = t >> 3;
  const int rc = (t & 7) * 4;

  float4 nrm4 = {0.f, 0.f, 0.f, 0.f};

  for (int p = 0; p < NSTEP; ++p) {
    const float4 v = *reinterpret_cast<const float4*>(
        w + (size_t)(p * BK + rk) * NCLS + c0 + rc);
    nrm4.x += v.x * v.x; nrm4.y += v.y * v.y;
    nrm4.z += v.z * v.z; nrm4.w += v.w * v.w;
    __syncthreads();
    *reinterpret_cast<float4*>(&S[rk][rc]) = v;
    __syncthreads();

    if (t < 128) {
      const int l2 = t & 63;
      const int j  = t >> 6;
      const int col = j * 16 + (l2 & 15);
      const int kb  = (l2 >> 4) * 8;
      uint4 pk;
      pk.x = (unsigned)f2bf(S[kb + 0][col]) | ((unsigned)f2bf(S[kb + 1][col]) << 16);
      pk.y = (unsigned)f2bf(S[kb + 2][col]) | ((unsigned)f2bf(S[kb + 3][col]) << 16);
      pk.z = (unsigned)f2bf(S[kb + 4][col]) | ((unsigned)f2bf(S[kb + 5][col]) << 16);
      pk.w = (unsigned)f2bf(S[kb + 6][col]) | ((unsigned)f2bf(S[kb + 7][col]) << 16);
      *reinterpret_cast<uint4*>(
          &bfrag[(((size_t)(cb * NSTEP + p) * 2 + j) * 64 + l2) * 8]) = pk;
    }
  }

  NRM[rk][rc + 0] = nrm4.x;
  NRM[rk][rc + 1] = nrm4.y;
  NRM[rk][rc + 2] = nrm4.z;
  NRM[rk][rc + 3] = nrm4.w;
  __syncthreads();
  if (t < 32) {
    float s = 0.f;
#pragma unroll
    for (int g = 0; g < 32; ++g) s += NRM[g][t];
    rnorm[c0 + t] = rsqrtf(fmaxf(s, 1e-20f));
  }
}

// ---------------------------------------------------------------------------
// DIAGNOSTIC: r8 K-loop verbatim, epilogue replaced by checksum (keeps acc,
// labL, and all loads/MFMAs live -- no DCE). Writes junk to ws.
// ---------------------------------------------------------------------------
__global__ __launch_bounds__(512, 4)
void abl_kloop(const unsigned short* __restrict__ bfrag,
               const unsigned short* __restrict__ afrag,
               const float* __restrict__ tgt,
               float* __restrict__ junk) {
  __shared__ unsigned char labL[NROWS];

  const int tid = threadIdx.x;
  const int wv  = tid >> 6;
  const int l   = tid & 63;
  const int c0  = blockIdx.x * BC;

  if (tid < 128) reinterpret_cast<unsigned*>(labL)[tid] = 0u;
  __syncthreads();

  const int trow0 = wv * 64 + (l >> 3) * 8;
  const int tcc   = (l & 7) * 4;
  const float* tgtp = tgt + (size_t)trow0 * NCLS + c0 + tcc;

  const unsigned short* pA = afrag + ((size_t)(wv * 4) * 64 + l) * 8;
  const unsigned short* pB = bfrag + ((size_t)(blockIdx.x * NSTEP) * 2 * 64 + l) * 8;

  f32x4 acc[4][2] = {};

#pragma unroll
  for (int ks = 0; ks < NSTEP; ++ks) {
    const bf16x8 b0 = *reinterpret_cast<const bf16x8*>(pB + (size_t)ks * 1024);
    const bf16x8 b1 = *reinterpret_cast<const bf16x8*>(pB + (size_t)ks * 1024 + 512);
    bf16x8 a[4];
#pragma unroll
    for (int i = 0; i < 4; ++i)
      a[i] = *reinterpret_cast<const bf16x8*>(pA + (size_t)(ks * MT + i) * 512);

    if ((ks & 1) == 0) {
      const int it = ks >> 1;
      const float4 tv = *reinterpret_cast<const float4*>(tgtp + (size_t)it * NCLS);
      const int trow = trow0 + it;
      if (tv.x > 0.5f) labL[trow] = (unsigned char)(tcc + 1);
      if (tv.y > 0.5f) labL[trow] = (unsigned char)(tcc + 2);
      if (tv.z > 0.5f) labL[trow] = (unsigned char)(tcc + 3);
      if (tv.w > 0.5f) labL[trow] = (unsigned char)(tcc + 4);
    }

#pragma unroll
    for (int i = 0; i < 4; ++i) {
      acc[i][0] = MFMA16(a[i], b0, acc[i][0]);
      acc[i][1] = MFMA16(a[i], b1, acc[i][1]);
    }
  }

  __syncthreads();
  float s = 0.f;
#pragma unroll
  for (int i = 0; i < 4; ++i)
#pragma unroll
    for (int j = 0; j < 2; ++j)
#pragma unroll
      for (int q = 0; q < 4; ++q) s += acc[i][j][q];
  s += (float)labL[tid];
  junk[(blockIdx.x & 63) * 512 + tid] = s;   // 128 KB window, races are fine (junk)
}

// ---------------------------------------------------------------------------
// Main kernel v9: r8 K-loop + fixed-shift epilogue (no per-column max pass).
// ---------------------------------------------------------------------------
__global__ __launch_bounds__(512, 4)
void arcface_main(const unsigned short* __restrict__ bfrag,
                  const unsigned short* __restrict__ afrag,
                  const float* __restrict__ rnorm,
                  const float* __restrict__ tgt,
                  float* __restrict__ out) {
  __shared__ float red[8][BC];
  __shared__ float colv[BC];
  __shared__ unsigned char labL[NROWS];

  const int tid = threadIdx.x;
  const int wv  = tid >> 6;
  const int l   = tid & 63;
  const int lh  = l >> 4;
  const int ll  = l & 15;
  const int c0  = blockIdx.x * BC;

  if (tid < 128) reinterpret_cast<unsigned*>(labL)[tid] = 0u;
  __syncthreads();

  const int trow0 = wv * 64 + (l >> 3) * 8;
  const int tcc   = (l & 7) * 4;
  const float* tgtp = tgt + (size_t)trow0 * NCLS + c0 + tcc;

  const unsigned short* pA = afrag + ((size_t)(wv * 4) * 64 + l) * 8;
  const unsigned short* pB = bfrag + ((size_t)(blockIdx.x * NSTEP) * 2 * 64 + l) * 8;

  f32x4 acc[4][2] = {};

#pragma unroll
  for (int ks = 0; ks < NSTEP; ++ks) {
    const bf16x8 b0 = *reinterpret_cast<const bf16x8*>(pB + (size_t)ks * 1024);
    const bf16x8 b1 = *reinterpret_cast<const bf16x8*>(pB + (size_t)ks * 1024 + 512);
    bf16x8 a[4];
#pragma unroll
    for (int i = 0; i < 4; ++i)
      a[i] = *reinterpret_cast<const bf16x8*>(pA + (size_t)(ks * MT + i) * 512);

    if ((ks & 1) == 0) {
      const int it = ks >> 1;
      const float4 tv = *reinterpret_cast<const float4*>(tgtp + (size_t)it * NCLS);
      const int trow = trow0 + it;
      if (tv.x > 0.5f) labL[trow] = (unsigned char)(tcc + 1);
      if (tv.y > 0.5f) labL[trow] = (unsigned char)(tcc + 2);
      if (tv.z > 0.5f) labL[trow] = (unsigned char)(tcc + 3);
      if (tv.w > 0.5f) labL[trow] = (unsigned char)(tcc + 4);
    }

#pragma unroll
    for (int i = 0; i < 4; ++i) {
      acc[i][0] = MFMA16(a[i], b0, acc[i][0]);
      acc[i][1] = MFMA16(a[i], b1, acc[i][1]);
    }
  }

  // ---- epilogue (fixed-shift softmax: no per-column max pass)
  float rn[2];
#pragma unroll
  for (int j = 0; j < 2; ++j) rn[j] = rnorm[c0 + j * 16 + ll];

  __syncthreads();   // labL visibility

  int lab[4][4];
#pragma unroll
  for (int i = 0; i < 4; ++i)
#pragma unroll
    for (int q = 0; q < 4; ++q)
      lab[i][q] = (int)labL[wv * 64 + i * 16 + lh * 4 + q] - 1;  // local col or -1

  // logits -> exp(l - SHIFT) and per-column partial sums in one pass
  float sme[2] = {0.f, 0.f};
#pragma unroll
  for (int j = 0; j < 2; ++j) {
    const int jl = j * 16 + ll;
#pragma unroll
    for (int i = 0; i < 4; ++i) {
#pragma unroll
      for (int q = 0; q < 4; ++q) {
        float cosv = acc[i][j][q] * rn[j];
        cosv = fminf(fmaxf(cosv, -1.f), 1.f);
        float lg;
        if (lab[i][q] == jl) {
          const float s = sqrtf(fmaxf(1.f - cosv * cosv, 0.f));
          lg = cosv * COS_M - s * SIN_M;
        } else {
          lg = cosv;
        }
        const float e = __expf(lg * SCALE - SHIFT);
        acc[i][j][q] = e;
        sme[j] += e;
      }
    }
  }

  // sum over the 512 rows of each column
#pragma unroll
  for (int j = 0; j < 2; ++j) {
    sme[j] += __shfl_xor(sme[j], 16, 64);
    sme[j] += __shfl_xor(sme[j], 32, 64);
  }
  if (l < 16) {
#pragma unroll
    for (int j = 0; j < 2; ++j) red[wv][j * 16 + l] = sme[j];
  }
  __syncthreads();
  if (tid < BC) {
    float s = 0.f;
#pragma unroll
    for (int v2 = 0; v2 < 8; ++v2) s += red[v2][tid];
    colv[tid] = s;
  }
  __syncthreads();

  float rs[2];
#pragma unroll
  for (int j = 0; j < 2; ++j) rs[j] = 1.0f / colv[j * 16 + ll];

#pragma unroll
  for (int j = 0; j < 2; ++j) {
    const int cj = c0 + j * 16 + ll;
#pragma unroll
    for (int i = 0; i < 4; ++i) {
#pragma unroll
      for (int q = 0; q < 4; ++q) {
        const int row = wv * 64 + i * 16 + lh * 4 + q;
        out[(size_t)row * NCLS + cj] = acc[i][j][q] * rs[j];
      }
    }
  }
}

extern "C" void kernel_launch(void* const* d_in, const int* in_sizes, int n_in,
                              void* d_out, int out_size, void* d_ws, size_t ws_size,
                              hipStream_t stream) {
  const float* emb = (const float*)d_in[0];   // [512][512]
  const float* w   = (const float*)d_in[1];   // [512][100000]
  const float* tgt = (const float*)d_in[2];   // [512][100000]
  float* out = (float*)d_out;                 // [512][100000]

  char* ws = (char*)d_ws;
  unsigned short* afrag = (unsigned short*)(ws + 4096);          // 512 KB
  float* rnorm          = (float*)(ws + (1u << 20));             // 400 KB
  unsigned short* bfrag = (unsigned short*)(ws + (2u << 20));    // 100 MB
  float* junk           = (float*)(ws + (104u << 20));           // 128 KB diag

  prep_afrag<<<64, 512, 0, stream>>>(emb, afrag);
  wt_kernel<<<NBLK, 256, 0, stream>>>(w, bfrag, rnorm);
  abl_kloop<<<NBLK, 512, 0, stream>>>(bfrag, afrag, tgt, junk);   // diagnostic
  arcface_main<<<NBLK, 512, 0, stream>>>(bfrag, afrag, rnorm, tgt, out);
}

// Round 10
// 296.176 us; speedup vs baseline: 1.4316x; 1.4316x over previous
//
#include <hip/hip_runtime.h>
#include <hip/hip_bf16.h>

// ArcFace fused: cos = emb @ (w/||w||), margin at target label, softmax over batch axis.
// N=512, D=512, C=100000 (= 3125*32, BC=32 exact), S=1.
//
//   prep_afrag : emb f32 -> bf16 A-fragments (512 KB, L2-resident)
//   wt_kernel  : w f32 -> bf16 B-fragments + rsqrt col norms (single pass, ~BW bound)
//   arcface_main: barrier-free LDS-free K-loop, HAND-PIPELINED (round-10 lever):
//       r9 ablation isolated K-loop = 155us vs 25us MFMA floor; VGPR_Count=52 showed
//       the compiler issues loads ~1 step ahead -> ~600cy HBM/L3 stall per step on the
//       bfrag/tgt streams. Fix: explicit register rings with compile-time indices:
//       bfrag depth-3 (ring-4), afrag depth-1 (ring-2), tgt depth-2-iters (ring-2).
//       ~119 regs/lane -> still 4 waves/SIMD (launch_bounds(512,4)).
//       Epilogue: fixed-shift softmax (logits in [-64,64] -> exp(l-20) always finite,
//       no per-column max pass; validated r9, absmax 0.0078).

static constexpr int DIM    = 512;
static constexpr int NROWS  = 512;
static constexpr int NCLS   = 100000;
static constexpr int BC     = 32;              // columns per block
static constexpr int BK     = 32;              // K per step
static constexpr int NSTEP  = DIM / BK;        // 16
static constexpr int MT     = NROWS / 16;      // 32
static constexpr int NBLK   = NCLS / BC;       // 3125 exact

static constexpr float COS_M = 0.87758256189037271611f;  // cos(0.5)
static constexpr float SIN_M = 0.47942553860420300027f;  // sin(0.5)
static constexpr float SCALE = 64.0f;
static constexpr float SHIFT = 20.0f;          // fixed softmax shift

typedef __attribute__((ext_vector_type(8))) short bf16x8;
typedef __attribute__((ext_vector_type(4))) float f32x4;

#define MFMA16(A, B, C) __builtin_amdgcn_mfma_f32_16x16x32_bf16((A), (B), (C), 0, 0, 0)

__device__ __forceinline__ unsigned short f2bf(float f) {
  union { float f; unsigned u; } v; v.f = f;
  unsigned u = v.u;
  return (unsigned short)((u + 0x7FFFu + ((u >> 16) & 1u)) >> 16);
}

// ---------------------------------------------------------------------------
__global__ void prep_afrag(const float* __restrict__ emb,
                           unsigned short* __restrict__ afrag) {
  const int idx = blockIdx.x * blockDim.x + threadIdx.x;  // 0..32767
  const int l  = idx & 63;
  const int mt = (idx >> 6) & 31;
  const int ks = idx >> 11;
  const int row = mt * 16 + (l & 15);
  const int k0  = ks * 32 + (l >> 4) * 8;

  unsigned short t[8];
#pragma unroll
  for (int j = 0; j < 8; ++j) t[j] = f2bf(emb[row * DIM + k0 + j]);

  uint4 v;
  v.x = (unsigned)t[0] | ((unsigned)t[1] << 16);
  v.y = (unsigned)t[2] | ((unsigned)t[3] << 16);
  v.z = (unsigned)t[4] | ((unsigned)t[5] << 16);
  v.w = (unsigned)t[6] | ((unsigned)t[7] << 16);
  *reinterpret_cast<uint4*>(&afrag[(size_t)idx * 8]) = v;
}

// ---------------------------------------------------------------------------
__global__ __launch_bounds__(256)
void wt_kernel(const float* __restrict__ w,
               unsigned short* __restrict__ bfrag,
               float* __restrict__ rnorm) {
  __shared__ float S[32][33];
  __shared__ float NRM[32][32];

  const int t  = threadIdx.x;
  const int cb = blockIdx.x;
  const int c0 = cb * 32;

  const int rk = t >> 3;
  const int rc = (t & 7) * 4;

  float4 nrm4 = {0.f, 0.f, 0.f, 0.f};

  for (int p = 0; p < NSTEP; ++p) {
    const float4 v = *reinterpret_cast<const float4*>(
        w + (size_t)(p * BK + rk) * NCLS + c0 + rc);
    nrm4.x += v.x * v.x; nrm4.y += v.y * v.y;
    nrm4.z += v.z * v.z; nrm4.w += v.w * v.w;
    __syncthreads();
    *reinterpret_cast<float4*>(&S[rk][rc]) = v;
    __syncthreads();

    if (t < 128) {
      const int l2 = t & 63;
      const int j  = t >> 6;
      const int col = j * 16 + (l2 & 15);
      const int kb  = (l2 >> 4) * 8;
      uint4 pk;
      pk.x = (unsigned)f2bf(S[kb + 0][col]) | ((unsigned)f2bf(S[kb + 1][col]) << 16);
      pk.y = (unsigned)f2bf(S[kb + 2][col]) | ((unsigned)f2bf(S[kb + 3][col]) << 16);
      pk.z = (unsigned)f2bf(S[kb + 4][col]) | ((unsigned)f2bf(S[kb + 5][col]) << 16);
      pk.w = (unsigned)f2bf(S[kb + 6][col]) | ((unsigned)f2bf(S[kb + 7][col]) << 16);
      *reinterpret_cast<uint4*>(
          &bfrag[(((size_t)(cb * NSTEP + p) * 2 + j) * 64 + l2) * 8]) = pk;
    }
  }

  NRM[rk][rc + 0] = nrm4.x;
  NRM[rk][rc + 1] = nrm4.y;
  NRM[rk][rc + 2] = nrm4.z;
  NRM[rk][rc + 3] = nrm4.w;
  __syncthreads();
  if (t < 32) {
    float s = 0.f;
#pragma unroll
    for (int g = 0; g < 32; ++g) s += NRM[g][t];
    rnorm[c0 + t] = rsqrtf(fmaxf(s, 1e-20f));
  }
}

// ---------------------------------------------------------------------------
// Main kernel. 512 threads = 8 waves, 2 blocks/CU. Hand-pipelined K-loop.
// ---------------------------------------------------------------------------
__global__ __launch_bounds__(512, 4)
void arcface_main(const unsigned short* __restrict__ bfrag,
                  const unsigned short* __restrict__ afrag,
                  const float* __restrict__ rnorm,
                  const float* __restrict__ tgt,
                  float* __restrict__ out) {
  __shared__ float red[8][BC];
  __shared__ float colv[BC];
  __shared__ unsigned char labL[NROWS];

  const int tid = threadIdx.x;
  const int wv  = tid >> 6;
  const int l   = tid & 63;
  const int lh  = l >> 4;
  const int ll  = l & 15;
  const int c0  = blockIdx.x * BC;

  if (tid < 128) reinterpret_cast<unsigned*>(labL)[tid] = 0u;
  __syncthreads();

  const int trow0 = wv * 64 + (l >> 3) * 8;
  const int tcc   = (l & 7) * 4;
  const float* tgtp = tgt + (size_t)trow0 * NCLS + c0 + tcc;

  const unsigned short* pA = afrag + ((size_t)(wv * 4) * 64 + l) * 8;
  const unsigned short* pB = bfrag + ((size_t)(blockIdx.x * NSTEP) * 2 * 64 + l) * 8;

  f32x4 acc[4][2] = {};

  // register rings (all indices compile-time constants after unroll)
  bf16x8 bp[4][2];   // bfrag ring: depth-3 prefetch
  bf16x8 ap[2][4];   // afrag ring: depth-1 prefetch
  float4 tp[2];      // tgt ring: depth-2 iterations (4 steps)

  // prologue
  bp[0][0] = *reinterpret_cast<const bf16x8*>(pB + 0 * 1024);
  bp[0][1] = *reinterpret_cast<const bf16x8*>(pB + 0 * 1024 + 512);
  bp[1][0] = *reinterpret_cast<const bf16x8*>(pB + 1 * 1024);
  bp[1][1] = *reinterpret_cast<const bf16x8*>(pB + 1 * 1024 + 512);
  bp[2][0] = *reinterpret_cast<const bf16x8*>(pB + 2 * 1024);
  bp[2][1] = *reinterpret_cast<const bf16x8*>(pB + 2 * 1024 + 512);
#pragma unroll
  for (int i = 0; i < 4; ++i)
    ap[0][i] = *reinterpret_cast<const bf16x8*>(pA + (size_t)(0 * MT + i) * 512);
  tp[0] = *reinterpret_cast<const float4*>(tgtp + (size_t)0 * NCLS);
  tp[1] = *reinterpret_cast<const float4*>(tgtp + (size_t)1 * NCLS);

#define STEP(KS)                                                                \
  {                                                                             \
    /* deep prefetches first: B at depth-3 (HBM/L3), A at depth-1 (L2) */       \
    if ((KS) + 3 < NSTEP) {                                                     \
      bp[((KS) + 3) & 3][0] =                                                   \
          *reinterpret_cast<const bf16x8*>(pB + (size_t)((KS) + 3) * 1024);     \
      bp[((KS) + 3) & 3][1] =                                                   \
          *reinterpret_cast<const bf16x8*>(pB + (size_t)((KS) + 3) * 1024 + 512);\
    }                                                                           \
    if ((KS) + 1 < NSTEP) {                                                     \
      ap[((KS) + 1) & 1][0] = *reinterpret_cast<const bf16x8*>(                 \
          pA + (size_t)(((KS) + 1) * MT + 0) * 512);                            \
      ap[((KS) + 1) & 1][1] = *reinterpret_cast<const bf16x8*>(                 \
          pA + (size_t)(((KS) + 1) * MT + 1) * 512);                            \
      ap[((KS) + 1) & 1][2] = *reinterpret_cast<const bf16x8*>(                 \
          pA + (size_t)(((KS) + 1) * MT + 2) * 512);                            \
      ap[((KS) + 1) & 1][3] = *reinterpret_cast<const bf16x8*>(                 \
          pA + (size_t)(((KS) + 1) * MT + 3) * 512);                            \
    }                                                                           \
    if (((KS) & 1) == 0) {                                                      \
      const int it = (KS) >> 1;                                                 \
      const float4 tv = tp[it & 1];                                            \
      const int trow = trow0 + it;                                             \
      if (tv.x > 0.5f) labL[trow] = (unsigned char)(tcc + 1);                  \
      if (tv.y > 0.5f) labL[trow] = (unsigned char)(tcc + 2);                  \
      if (tv.z > 0.5f) labL[trow] = (unsigned char)(tcc + 3);                  \
      if (tv.w > 0.5f) labL[trow] = (unsigned char)(tcc + 4);                  \
      if (it + 2 < 8)                                                          \
        tp[it & 1] = *reinterpret_cast<const float4*>(tgtp + (size_t)(it + 2) * NCLS); \
    }                                                                           \
    acc[0][0] = MFMA16(ap[(KS) & 1][0], bp[(KS) & 3][0], acc[0][0]);            \
    acc[0][1] = MFMA16(ap[(KS) & 1][0], bp[(KS) & 3][1], acc[0][1]);            \
    acc[1][0] = MFMA16(ap[(KS) & 1][1], bp[(KS) & 3][0], acc[1][0]);            \
    acc[1][1] = MFMA16(ap[(KS) & 1][1], bp[(KS) & 3][1], acc[1][1]);            \
    acc[2][0] = MFMA16(ap[(KS) & 1][2], bp[(KS) & 3][0], acc[2][0]);            \
    acc[2][1] = MFMA16(ap[(KS) & 1][2], bp[(KS) & 3][1], acc[2][1]);            \
    acc[3][0] = MFMA16(ap[(KS) & 1][3], bp[(KS) & 3][0], acc[3][0]);            \
    acc[3][1] = MFMA16(ap[(KS) & 1][3], bp[(KS) & 3][1], acc[3][1]);            \
  }

  STEP(0)  STEP(1)  STEP(2)  STEP(3)
  STEP(4)  STEP(5)  STEP(6)  STEP(7)
  STEP(8)  STEP(9)  STEP(10) STEP(11)
  STEP(12) STEP(13) STEP(14) STEP(15)
#undef STEP

  // ---- epilogue (fixed-shift softmax)
  float rn[2];
#pragma unroll
  for (int j = 0; j < 2; ++j) rn[j] = rnorm[c0 + j * 16 + ll];

  __syncthreads();   // labL visibility

  int lab[4][4];
#pragma unroll
  for (int i = 0; i < 4; ++i)
#pragma unroll
    for (int q = 0; q < 4; ++q)
      lab[i][q] = (int)labL[wv * 64 + i * 16 + lh * 4 + q] - 1;  // local col or -1

  float sme[2] = {0.f, 0.f};
#pragma unroll
  for (int j = 0; j < 2; ++j) {
    const int jl = j * 16 + ll;
#pragma unroll
    for (int i = 0; i < 4; ++i) {
#pragma unroll
      for (int q = 0; q < 4; ++q) {
        float cosv = acc[i][j][q] * rn[j];
        cosv = fminf(fmaxf(cosv, -1.f), 1.f);
        float lg;
        if (lab[i][q] == jl) {
          const float s = sqrtf(fmaxf(1.f - cosv * cosv, 0.f));
          lg = cosv * COS_M - s * SIN_M;
        } else {
          lg = cosv;
        }
        const float e = __expf(lg * SCALE - SHIFT);
        acc[i][j][q] = e;
        sme[j] += e;
      }
    }
  }

  // sum over the 512 rows of each column
#pragma unroll
  for (int j = 0; j < 2; ++j) {
    sme[j] += __shfl_xor(sme[j], 16, 64);
    sme[j] += __shfl_xor(sme[j], 32, 64);
  }
  if (l < 16) {
#pragma unroll
    for (int j = 0; j < 2; ++j) red[wv][j * 16 + l] = sme[j];
  }
  __syncthreads();
  if (tid < BC) {
    float s = 0.f;
#pragma unroll
    for (int v2 = 0; v2 < 8; ++v2) s += red[v2][tid];
    colv[tid] = s;
  }
  __syncthreads();

  float rs[2];
#pragma unroll
  for (int j = 0; j < 2; ++j) rs[j] = 1.0f / colv[j * 16 + ll];

#pragma unroll
  for (int j = 0; j < 2; ++j) {
    const int cj = c0 + j * 16 + ll;
#pragma unroll
    for (int i = 0; i < 4; ++i) {
#pragma unroll
      for (int q = 0; q < 4; ++q) {
        const int row = wv * 64 + i * 16 + lh * 4 + q;
        out[(size_t)row * NCLS + cj] = acc[i][j][q] * rs[j];
      }
    }
  }
}

extern "C" void kernel_launch(void* const* d_in, const int* in_sizes, int n_in,
                              void* d_out, int out_size, void* d_ws, size_t ws_size,
                              hipStream_t stream) {
  const float* emb = (const float*)d_in[0];   // [512][512]
  const float* w   = (const float*)d_in[1];   // [512][100000]
  const float* tgt = (const float*)d_in[2];   // [512][100000]
  float* out = (float*)d_out;                 // [512][100000]

  char* ws = (char*)d_ws;
  unsigned short* afrag = (unsigned short*)(ws + 4096);          // 512 KB
  float* rnorm          = (float*)(ws + (1u << 20));             // 400 KB
  unsigned short* bfrag = (unsigned short*)(ws + (2u << 20));    // 100 MB

  prep_afrag<<<64, 512, 0, stream>>>(emb, afrag);
  wt_kernel<<<NBLK, 256, 0, stream>>>(w, bfrag, rnorm);
  arcface_main<<<NBLK, 512, 0, stream>>>(bfrag, afrag, rnorm, tgt, out);
}